// Round 24
// baseline (179.484 us; speedup 1.0000x reference)
//
#include <hip/hip_runtime.h>
#include <hip/hip_fp16.h>

// ---------------------------------------------------------------------------
// GCN layer: out[b][f][t][n] = relu( rs_in[n] * (sum_{e:dst=n} rs_out[src]*x[src]) @ W + b )
// R24 restructure (reference order): (1) degrees+CSR, (2) k_convert:
//     transpose+rs_out-scale in_feat -> x'[n][512] fp16 (NO matmul),
//     (3) k_aggregate: CSR gather-sum of x' (identical body) + W-matmul
//     fused into the epilogue (8 MFMAs/wave, hidden in gather stall cycles).
//     W pre-transposed to Wt[f][h] fp16 (k_wt) so epilogue W-frags are
//     single uint4 loads. Fragment mapping = R23-verified swapped form.
// ---------------------------------------------------------------------------

typedef _Float16 half8 __attribute__((ext_vector_type(8)));
typedef float f32x4 __attribute__((ext_vector_type(4)));

extern "C" __global__ void k_deg(const int* __restrict__ src, const int* __restrict__ dst,
                                 int* __restrict__ deg_out, int* __restrict__ deg_in, int E) {
  int e = blockIdx.x * blockDim.x + threadIdx.x;
  if (e < E) {
    atomicAdd(&deg_out[src[e]], 1);
    atomicAdd(&deg_in[dst[e]], 1);
  }
}

// scan1 + rsqrt fused: block sums of deg_in, plus rs arrays.
extern "C" __global__ __launch_bounds__(256) void k_scan1(const int* __restrict__ deg_in,
                                                          const int* __restrict__ deg_out,
                                                          int* __restrict__ bsum,
                                                          float* __restrict__ rs_out,
                                                          float* __restrict__ rs_in, int N) {
  __shared__ int red[256];
  int tid = threadIdx.x;
  int i = blockIdx.x * 256 + tid;
  int di = (i < N) ? deg_in[i] : 0;
  red[tid] = di;
  if (i < N) {
    int a = deg_out[i] > 1 ? deg_out[i] : 1;
    int b = di > 1 ? di : 1;
    rs_out[i] = rsqrtf((float)a);
    rs_in[i]  = rsqrtf((float)b);
  }
  __syncthreads();
  #pragma unroll
  for (int off = 128; off > 0; off >>= 1) {
    if (tid < off) red[tid] += red[tid + off];
    __syncthreads();
  }
  if (tid == 0) bsum[blockIdx.x] = red[0];
}

// scan3: per-node exclusive scan + local bsum scan. offs[i] and cursor[i].
extern "C" __global__ __launch_bounds__(256) void k_scan3(const int* __restrict__ deg,
                                                          const int* __restrict__ bsum,
                                                          int* __restrict__ offs,
                                                          int* __restrict__ cursor,
                                                          int M, int N) {
  __shared__ int sc[256];
  __shared__ int bs[256];
  int tid = threadIdx.x;

  int bv = (tid < M) ? bsum[tid] : 0;
  bs[tid] = bv;
  __syncthreads();
  #pragma unroll
  for (int off = 1; off < 256; off <<= 1) {
    int t = bs[tid];
    if (tid >= off) t += bs[tid - off];
    __syncthreads();
    bs[tid] = t;
    __syncthreads();
  }
  int boff = (blockIdx.x > 0) ? bs[blockIdx.x - 1] : 0;
  if (blockIdx.x == 0 && tid == 0) offs[N] = bs[255];  // total edges

  int i = blockIdx.x * 256 + tid;
  int v = (i < N) ? deg[i] : 0;
  sc[tid] = v;
  __syncthreads();
  #pragma unroll
  for (int off = 1; off < 256; off <<= 1) {
    int t = sc[tid];
    if (tid >= off) t += sc[tid - off];
    __syncthreads();
    sc[tid] = t;
    __syncthreads();
  }
  if (i < N) {
    int o = boff + sc[tid] - v;
    offs[i] = o;
    cursor[i] = o;
  }
}

extern "C" __global__ void k_scatter(const int* __restrict__ src, const int* __restrict__ dst,
                                     int* __restrict__ cursor,
                                     int* __restrict__ csr_src, int E) {
  int e = blockIdx.x * blockDim.x + threadIdx.x;
  if (e < E) {
    int pos = atomicAdd(&cursor[dst[e]], 1);
    csr_src[pos] = src[e];
  }
}

// Wt[f*64+h] = (half)W[h*64+f] — one tiny block.
extern "C" __global__ __launch_bounds__(256) void k_wt(const float* __restrict__ W,
                                                       __half* __restrict__ Wt) {
  int tid = threadIdx.x;
  for (int i = tid; i < 4096; i += 256) {
    int f = i >> 6, h = i & 63;
    Wt[f * 64 + h] = __float2half(W[h * 64 + f]);
  }
}

// Convert: in_feat -> x'[n][512] fp16, rs_out folded. Block = 256 thr, 64
// nodes x 2 bt (grid (N/64, 4)). Stage xs[h][n] via float4 (coalesced),
// LDS-transpose, write 2x uint4 per thread per bt. No matmul.
extern "C" __global__ __launch_bounds__(256) void k_convert(
    const float* __restrict__ in_feat, const float* __restrict__ rs_out,
    __half* __restrict__ xh, int N) {
  __shared__ __half xs[64][68];
  int tid = threadIdx.x;
  int n0 = blockIdx.x * 64;

  int hq = tid >> 4, nq = tid & 15;
  int nb = n0 + 4 * nq;
  float rs4[4];
  #pragma unroll
  for (int c = 0; c < 4; ++c)
    rs4[c] = (nb + c < N) ? rs_out[nb + c] : 0.0f;
  bool full4 = (nb + 3 < N);

  int node = tid >> 2, sg = tid & 3;
  int nr = n0 + node;

  #pragma unroll
  for (int p = 0; p < 2; ++p) {
    int bt = blockIdx.y * 2 + p;
    int b = bt >> 2, t = bt & 3;
    const float* xbase = in_feat + (size_t)(b * 256 + t) * (size_t)N;

    __syncthreads();
    #pragma unroll
    for (int i = 0; i < 4; ++i) {
      int h = hq + 16 * i;
      const float* xp = xbase + (size_t)h * 4 * (size_t)N + nb;
      float v0 = 0.f, v1 = 0.f, v2 = 0.f, v3 = 0.f;
      if (full4) {
        float4 v = *(const float4*)xp;
        v0 = v.x; v1 = v.y; v2 = v.z; v3 = v.w;
      } else {
        if (nb < N)     v0 = xp[0];
        if (nb + 1 < N) v1 = xp[1];
        if (nb + 2 < N) v2 = xp[2];
      }
      __half2 h0 = __float22half2_rn(make_float2(v0 * rs4[0], v1 * rs4[1]));
      __half2 h1 = __float22half2_rn(make_float2(v2 * rs4[2], v3 * rs4[3]));
      uint2 u;
      u.x = *(unsigned int*)&h0;
      u.y = *(unsigned int*)&h1;
      *(uint2*)&xs[h][4 * nq] = u;
    }
    __syncthreads();

    // transpose-write: thread -> (node, 16-h group sg)
    if (nr < N) {
      __half tmp[16];
      #pragma unroll
      for (int u = 0; u < 16; ++u) tmp[u] = xs[sg * 16 + u][node];
      uint4* gp = (uint4*)(xh + (size_t)nr * 512 + bt * 64 + sg * 16);
      gp[0] = *(const uint4*)&tmp[0];
      gp[1] = *(const uint4*)&tmp[8];
    }
  }
}

// Aggregate + fused W-matmul epilogue. Gather body = R9 (2x8B/edge, unroll
// 4) on x'. Epilogue: wave w handles bt=w; B-frags from agg LDS columns
// (fp32->fp16, x rs_in), W-frags = single uint4 loads from Wt; 8 MFMAs;
// D[f][node] stored bias+relu+NT, 64B-coalesced.
extern "C" __global__ __launch_bounds__(512) void k_aggregate(
    const __half* __restrict__ y, const int* __restrict__ offs,
    const int* __restrict__ csr_src, const float* __restrict__ rs_in,
    const __half* __restrict__ Wt,
    const float* __restrict__ bvec, float* __restrict__ out, int N) {
  __shared__ float agg[16 * 513];
  int tid = threadIdx.x;
  int lane = tid & 63, wave = tid >> 6;   // 8 waves
  int n0 = blockIdx.x * 16;

#define ACC_EDGE(s)                                                          \
  {                                                                          \
    const uint2* rp = (const uint2*)(y + (size_t)(s) * 512);                 \
    uint2 ua = rp[lane];                                                     \
    uint2 ub = rp[64 + lane];                                                \
    float2 f;                                                                \
    f = __half22float2(*(const __half2*)&ua.x); accA.x += f.x; accA.y += f.y;\
    f = __half22float2(*(const __half2*)&ua.y); accA.z += f.x; accA.w += f.y;\
    f = __half22float2(*(const __half2*)&ub.x); accB.x += f.x; accB.y += f.y;\
    f = __half22float2(*(const __half2*)&ub.y); accB.z += f.x; accB.w += f.y;\
  }

  #pragma unroll
  for (int k = 0; k < 2; ++k) {
    int nl = k * 8 + wave;
    int n = n0 + nl;
    float4 accA = {0.f, 0.f, 0.f, 0.f};
    float4 accB = {0.f, 0.f, 0.f, 0.f};
    if (n < N) {
      int j0 = offs[n], j1 = offs[n + 1];
      for (int base = j0; base < j1; base += 64) {
        int idxv = csr_src[base + lane];
        int m = j1 - base; if (m > 64) m = 64;
        int e = 0;
        for (; e + 3 < m; e += 4) {
          int s0 = __builtin_amdgcn_readlane(idxv, e);
          int s1 = __builtin_amdgcn_readlane(idxv, e + 1);
          int s2 = __builtin_amdgcn_readlane(idxv, e + 2);
          int s3 = __builtin_amdgcn_readlane(idxv, e + 3);
          ACC_EDGE(s0); ACC_EDGE(s1); ACC_EDGE(s2); ACC_EDGE(s3);
        }
        for (; e < m; ++e) {
          int s0 = __builtin_amdgcn_readlane(idxv, e);
          ACC_EDGE(s0);
        }
      }
    }
    *(float4*)&agg[nl * 513 + lane * 4] = accA;
    *(float4*)&agg[nl * 513 + 256 + lane * 4] = accB;
  }
#undef ACC_EDGE
  __syncthreads();

  // epilogue: wave w -> bt = w. col = node, kg = k-group (R23-verified map).
  int bt = wave;
  int b = bt >> 2, t = bt & 3;
  int col = lane & 15, kg = lane >> 4;
  int n = n0 + col;
  float rsi = (n < N) ? rs_in[n] : 0.0f;

  // B-frags: agg column reads (<=2-way banks), fp16 cvt, rs_in folded
  half8 xb0, xb1;
  #pragma unroll
  for (int j = 0; j < 8; ++j)
    xb0[j] = (_Float16)(agg[col * 513 + bt * 64 + kg * 8 + j] * rsi);
  #pragma unroll
  for (int j = 0; j < 8; ++j)
    xb1[j] = (_Float16)(agg[col * 513 + bt * 64 + 32 + kg * 8 + j] * rsi);

  #pragma unroll
  for (int ft = 0; ft < 4; ++ft) {
    // W-frags: Wt[f=ft*16+col][k] contiguous -> one uint4 each
    uint4 w0u = *(const uint4*)(Wt + ((ft * 16 + col) * 64 + kg * 8));
    uint4 w1u = *(const uint4*)(Wt + ((ft * 16 + col) * 64 + 32 + kg * 8));
    half8 w0 = *(const half8*)&w0u;
    half8 w1 = *(const half8*)&w1u;
    f32x4 acc = {0.f, 0.f, 0.f, 0.f};
    acc = __builtin_amdgcn_mfma_f32_16x16x32_f16(w0, xb0, acc, 0, 0, 0);
    acc = __builtin_amdgcn_mfma_f32_16x16x32_f16(w1, xb1, acc, 0, 0, 0);
    #pragma unroll
    for (int r = 0; r < 4; ++r) {
      int f = ft * 16 + kg * 4 + r;
      float v = acc[r] + bvec[f];
      v = fmaxf(v, 0.0f);
      if (n < N)
        __builtin_nontemporal_store(v, &out[(size_t)((b * 64 + f) * 4 + t) * (size_t)N + n]);
    }
  }
}

extern "C" void kernel_launch(void* const* d_in, const int* in_sizes, int n_in,
                              void* d_out, int out_size, void* d_ws, size_t ws_size,
                              hipStream_t stream) {
  const float* in_feat = (const float*)d_in[0];
  const int*   src     = (const int*)d_in[1];
  const int*   dst     = (const int*)d_in[2];
  const float* W       = (const float*)d_in[3];
  const float* bvec    = (const float*)d_in[4];
  float* out = (float*)d_out;

  int N = in_sizes[0] / 512;   // B*H*T = 2*64*4 = 512
  int E = in_sizes[1];

  int A  = (N + 64) & ~63;
  int EA = (E + 63) & ~63;
  int M  = (N + 255) / 256;
  int GX = (N + 63) / 64;

  int*    deg_out_i = (int*)d_ws;        // [A]  zeroed
  int*    deg_in_i  = deg_out_i + A;     // [A]  zeroed
  int*    cursor    = deg_in_i + A;      // [A]  written by scan3
  int*    offs      = cursor + A;        // [A]  (N+1 used)
  int*    bsum      = offs + A;          // [256]
  __half* Wt        = (__half*)(bsum + 256);   // [4096] halfs = 2048 ints
  float*  rs_out    = (float*)(Wt + 4096);
  float*  rs_in     = rs_out + A;
  int*    csr_src   = (int*)(rs_in + A); // [EA]
  __half* xh        = (__half*)(csr_src + EA); // [N*512] fp16 node-major

  hipMemsetAsync(deg_out_i, 0, (size_t)(2 * A) * sizeof(int), stream);
  hipLaunchKernelGGL(k_deg, dim3((E + 255) / 256), dim3(256), 0, stream,
                     src, dst, deg_out_i, deg_in_i, E);
  hipLaunchKernelGGL(k_scan1, dim3(M), dim3(256), 0, stream,
                     deg_in_i, deg_out_i, bsum, rs_out, rs_in, N);
  hipLaunchKernelGGL(k_scan3, dim3(M), dim3(256), 0, stream,
                     deg_in_i, bsum, offs, cursor, M, N);
  hipLaunchKernelGGL(k_scatter, dim3((E + 255) / 256), dim3(256), 0, stream,
                     src, dst, cursor, csr_src, E);
  hipLaunchKernelGGL(k_wt, dim3(1), dim3(256), 0, stream, W, Wt);
  hipLaunchKernelGGL(k_convert, dim3(GX, 4), dim3(256), 0, stream,
                     in_feat, rs_out, xh, N);
  hipLaunchKernelGGL(k_aggregate, dim3((N + 15) / 16), dim3(512), 0, stream,
                     xh, offs, csr_src, rs_in, Wt, bvec, out, N);
}

// Round 25
// 173.389 us; speedup vs baseline: 1.0352x; 1.0352x over previous
//
#include <hip/hip_runtime.h>
#include <hip/hip_fp16.h>

// ---------------------------------------------------------------------------
// GCN layer: out[b][f][t][n] = relu( rsqrt(deg_in[n]) *
//     sum_{e: dst[e]=n} ( rsqrt(deg_out[src[e]]) * x[src[e]] @ W )[b][t][f] + bias[f] )
// Strategy: (1) degrees+CSR, (2) MFMA transform -> y[n][512] fp16 plain
//           node-major, (3) CSR gather-sum + epilogue + transpose-back.
// R25 = R22 revert (measured best, 173.7us). R23 (operand swap) and R24
//      (fused epilogue) both regressed; R24 proved transform's limiter is
//      the strided x read/transpose path (convert-without-MFMA = same cost).
//      Aggregate fabric-pinned at 4.1 TB/s. This is the consolidation build.
// ---------------------------------------------------------------------------

typedef _Float16 half8 __attribute__((ext_vector_type(8)));
typedef float f32x4 __attribute__((ext_vector_type(4)));

extern "C" __global__ void k_deg(const int* __restrict__ src, const int* __restrict__ dst,
                                 int* __restrict__ deg_out, int* __restrict__ deg_in, int E) {
  int e = blockIdx.x * blockDim.x + threadIdx.x;
  if (e < E) {
    atomicAdd(&deg_out[src[e]], 1);
    atomicAdd(&deg_in[dst[e]], 1);
  }
}

// scan1 + rsqrt fused: block sums of deg_in, plus rs arrays.
extern "C" __global__ __launch_bounds__(256) void k_scan1(const int* __restrict__ deg_in,
                                                          const int* __restrict__ deg_out,
                                                          int* __restrict__ bsum,
                                                          float* __restrict__ rs_out,
                                                          float* __restrict__ rs_in, int N) {
  __shared__ int red[256];
  int tid = threadIdx.x;
  int i = blockIdx.x * 256 + tid;
  int di = (i < N) ? deg_in[i] : 0;
  red[tid] = di;
  if (i < N) {
    int a = deg_out[i] > 1 ? deg_out[i] : 1;
    int b = di > 1 ? di : 1;
    rs_out[i] = rsqrtf((float)a);
    rs_in[i]  = rsqrtf((float)b);
  }
  __syncthreads();
  #pragma unroll
  for (int off = 128; off > 0; off >>= 1) {
    if (tid < off) red[tid] += red[tid + off];
    __syncthreads();
  }
  if (tid == 0) bsum[blockIdx.x] = red[0];
}

// scan3 (scan2 folded in): per-node exclusive scan within block + local scan
// of bsum for the block offset. Writes offs[i] AND cursor[i]=offs[i].
extern "C" __global__ __launch_bounds__(256) void k_scan3(const int* __restrict__ deg,
                                                          const int* __restrict__ bsum,
                                                          int* __restrict__ offs,
                                                          int* __restrict__ cursor,
                                                          int M, int N) {
  __shared__ int sc[256];
  __shared__ int bs[256];
  int tid = threadIdx.x;

  int bv = (tid < M) ? bsum[tid] : 0;
  bs[tid] = bv;
  __syncthreads();
  #pragma unroll
  for (int off = 1; off < 256; off <<= 1) {
    int t = bs[tid];
    if (tid >= off) t += bs[tid - off];
    __syncthreads();
    bs[tid] = t;
    __syncthreads();
  }
  int boff = (blockIdx.x > 0) ? bs[blockIdx.x - 1] : 0;
  if (blockIdx.x == 0 && tid == 0) offs[N] = bs[255];  // total edges

  int i = blockIdx.x * 256 + tid;
  int v = (i < N) ? deg[i] : 0;
  sc[tid] = v;
  __syncthreads();
  #pragma unroll
  for (int off = 1; off < 256; off <<= 1) {
    int t = sc[tid];
    if (tid >= off) t += sc[tid - off];
    __syncthreads();
    sc[tid] = t;
    __syncthreads();
  }
  if (i < N) {
    int o = boff + sc[tid] - v;
    offs[i] = o;
    cursor[i] = o;   // preload for scatter's single-atomic path
  }
}

extern "C" __global__ void k_scatter(const int* __restrict__ src, const int* __restrict__ dst,
                                     int* __restrict__ cursor,
                                     int* __restrict__ csr_src, int E) {
  int e = blockIdx.x * blockDim.x + threadIdx.x;
  if (e < E) {
    int pos = atomicAdd(&cursor[dst[e]], 1);
    csr_src[pos] = src[e];
  }
}

// MFMA transform (R22). Block = 256 thr = 4 waves; grid (ceil(N/64), 4).
// Block covers nodes n0..n0+63 for bt = blockIdx.y*2+{0,1}. Per bt: stage x
// (float4, rs-scaled, fp16) -> xs[64][68]; wave w computes nodes n0+16w..+15
// (A-frags from xs, 8 MFMAs, D -> yt); block-wide uint4 y store
// (2 uint4/thread = full 64-half rows). W frags VGPR-resident.
extern "C" __global__ __launch_bounds__(256) void k_transform(
    const float* __restrict__ in_feat, const float* __restrict__ W,
    const float* __restrict__ rs_out, __half* __restrict__ y, int N) {
  __shared__ __half xs[64][68];   // x tile: [h][n], stride 68 (frag reads 2-way-free)
  __shared__ __half yt[64][72];   // y tile: [node][ch], 144B rows (16B aligned)
  int tid = threadIdx.x;
  int wave = tid >> 6, l = tid & 63;
  int col = l & 15;      // node-within-subtile on A side; f-within-tile on D side
  int kg  = l >> 4;      // k-group 0..3
  int n0 = blockIdx.x * 64;

  // W fragments (VGPR-resident): wf[ft][ks][j] = W[(ks*32+kg*8+j)*64 + ft*16 + col]
  half8 wf[4][2];
  #pragma unroll
  for (int ft = 0; ft < 4; ++ft)
    #pragma unroll
    for (int ks = 0; ks < 2; ++ks)
      #pragma unroll
      for (int j = 0; j < 8; ++j)
        wf[ft][ks][j] = (_Float16)W[(ks * 32 + kg * 8 + j) * 64 + ft * 16 + col];

  // staging thread mapping: hq = tid>>4 (16 h-slots), nq = tid&15 (4-node cols)
  int hq = tid >> 4, nq = tid & 15;
  int nb = n0 + 4 * nq;
  float rs4[4];
  #pragma unroll
  for (int c = 0; c < 4; ++c)
    rs4[c] = (nb + c < N) ? rs_out[nb + c] : 0.0f;
  bool full4 = (nb + 3 < N);

  #pragma unroll
  for (int p = 0; p < 2; ++p) {
    int bt = blockIdx.y * 2 + p;
    int b = bt >> 2, t = bt & 3;
    const float* xbase = in_feat + (size_t)(b * 256 + t) * (size_t)N;

    __syncthreads();   // xs/yt safe to overwrite (prev pass readers done)
    // stage: 4 float4 rows per thread (h = hq + 16i), 1KB/instr per wave
    #pragma unroll
    for (int i = 0; i < 4; ++i) {
      int h = hq + 16 * i;
      const float* xp = xbase + (size_t)h * 4 * (size_t)N + nb;
      float v0 = 0.f, v1 = 0.f, v2 = 0.f, v3 = 0.f;
      if (full4) {
        float4 v = *(const float4*)xp;
        v0 = v.x; v1 = v.y; v2 = v.z; v3 = v.w;
      } else {
        if (nb < N)     v0 = xp[0];
        if (nb + 1 < N) v1 = xp[1];
        if (nb + 2 < N) v2 = xp[2];
      }
      __half2 h0 = __float22half2_rn(make_float2(v0 * rs4[0], v1 * rs4[1]));
      __half2 h1 = __float22half2_rn(make_float2(v2 * rs4[2], v3 * rs4[3]));
      uint2 u;
      u.x = *(unsigned int*)&h0;
      u.y = *(unsigned int*)&h1;
      *(uint2*)&xs[h][4 * nq] = u;
    }
    __syncthreads();

    // A-fragments from LDS: wave w owns nodes n0+16w+col
    int nloc = 16 * wave + col;
    half8 a0, a1;
    #pragma unroll
    for (int j = 0; j < 8; ++j) a0[j] = (_Float16)xs[kg * 8 + j][nloc];
    #pragma unroll
    for (int j = 0; j < 8; ++j) a1[j] = (_Float16)xs[32 + kg * 8 + j][nloc];

    #pragma unroll
    for (int ft = 0; ft < 4; ++ft) {
      f32x4 acc = {0.f, 0.f, 0.f, 0.f};
      acc = __builtin_amdgcn_mfma_f32_16x16x32_f16(a0, wf[ft][0], acc, 0, 0, 0);
      acc = __builtin_amdgcn_mfma_f32_16x16x32_f16(a1, wf[ft][1], acc, 0, 0, 0);
      #pragma unroll
      for (int r = 0; r < 4; ++r)
        yt[16 * wave + kg * 4 + r][ft * 16 + col] = __float2half(acc[r]);
    }
    __syncthreads();

    // y store: node = tid>>2 (64 nodes), sg = tid&3; TWO uint4 per thread
    // (sg and sg+4) = full 64-half (128B) row slice.
    int node = tid >> 2, sg = tid & 3;
    int nr = n0 + node;
    if (nr < N) {
      uint4* gp = (uint4*)(y + (size_t)nr * 512 + bt * 64);
      gp[sg]     = *(const uint4*)&yt[node][sg * 8];
      gp[sg + 4] = *(const uint4*)&yt[node][(sg + 4) * 8];
    }
  }
}

// Aggregate (R9 body + R17 NT out stores — 72.3us, fabric-pinned, frozen).
extern "C" __global__ __launch_bounds__(512) void k_aggregate(
    const __half* __restrict__ y, const int* __restrict__ offs,
    const int* __restrict__ csr_src, const float* __restrict__ rs_in,
    const float* __restrict__ bvec, float* __restrict__ out, int N) {
  __shared__ float agg[16 * 513];
  int tid = threadIdx.x;
  int lane = tid & 63, wave = tid >> 6;   // 8 waves
  int n0 = blockIdx.x * 16;

#define ACC_EDGE(s)                                                          \
  {                                                                          \
    const uint2* rp = (const uint2*)(y + (size_t)(s) * 512);                 \
    uint2 ua = rp[lane];                                                     \
    uint2 ub = rp[64 + lane];                                                \
    float2 f;                                                                \
    f = __half22float2(*(const __half2*)&ua.x); accA.x += f.x; accA.y += f.y;\
    f = __half22float2(*(const __half2*)&ua.y); accA.z += f.x; accA.w += f.y;\
    f = __half22float2(*(const __half2*)&ub.x); accB.x += f.x; accB.y += f.y;\
    f = __half22float2(*(const __half2*)&ub.y); accB.z += f.x; accB.w += f.y;\
  }

  #pragma unroll
  for (int k = 0; k < 2; ++k) {
    int nl = k * 8 + wave;
    int n = n0 + nl;
    float4 accA = {0.f, 0.f, 0.f, 0.f};
    float4 accB = {0.f, 0.f, 0.f, 0.f};
    if (n < N) {
      int j0 = offs[n], j1 = offs[n + 1];
      for (int base = j0; base < j1; base += 64) {
        int idxv = csr_src[base + lane];  // coalesced block of up to 64 indices
        int m = j1 - base; if (m > 64) m = 64;
        int e = 0;
        for (; e + 3 < m; e += 4) {
          int s0 = __builtin_amdgcn_readlane(idxv, e);
          int s1 = __builtin_amdgcn_readlane(idxv, e + 1);
          int s2 = __builtin_amdgcn_readlane(idxv, e + 2);
          int s3 = __builtin_amdgcn_readlane(idxv, e + 3);
          ACC_EDGE(s0); ACC_EDGE(s1); ACC_EDGE(s2); ACC_EDGE(s3);
        }
        for (; e < m; ++e) {
          int s0 = __builtin_amdgcn_readlane(idxv, e);
          ACC_EDGE(s0);
        }
      }
    }
    *(float4*)&agg[nl * 513 + lane * 4] = accA;
    *(float4*)&agg[nl * 513 + 256 + lane * 4] = accB;
  }
#undef ACC_EDGE
  __syncthreads();

  // epilogue: scale, bias, relu, transpose-back; NT stores (R17).
  int nl = tid & 15;
  int r0 = tid >> 4;  // 0..31
  int n = n0 + nl;
  float rs = (n < N) ? rs_in[n] : 0.0f;
  #pragma unroll 4
  for (int it = 0; it < 16; ++it) {
    int c = it * 32 + r0;          // c = (b*4+t)*64 + f
    float v = agg[nl * 513 + c];
    int f = c & 63, bt = c >> 6;
    int b = bt >> 2, t = bt & 3;
    v = v * rs + bvec[f];
    v = fmaxf(v, 0.0f);
    if (n < N)
      __builtin_nontemporal_store(v, &out[(size_t)((b * 64 + f) * 4 + t) * (size_t)N + n]);
  }
}

extern "C" void kernel_launch(void* const* d_in, const int* in_sizes, int n_in,
                              void* d_out, int out_size, void* d_ws, size_t ws_size,
                              hipStream_t stream) {
  const float* in_feat = (const float*)d_in[0];
  const int*   src     = (const int*)d_in[1];
  const int*   dst     = (const int*)d_in[2];
  const float* W       = (const float*)d_in[3];
  const float* bvec    = (const float*)d_in[4];
  float* out = (float*)d_out;

  int N = in_sizes[0] / 512;   // B*H*T = 2*64*4 = 512
  int E = in_sizes[1];

  int A  = (N + 64) & ~63;     // room for N+1 offsets, 64-aligned
  int EA = (E + 63) & ~63;
  int M  = (N + 255) / 256;    // scan blocks (<= 256 for N <= 65536)
  int GX = (N + 63) / 64;      // transform blocks (64-node tiles)

  // layout: the two arrays needing zero-init come first (one memset)
  int*   deg_out_i = (int*)d_ws;        // [A]  zeroed
  int*   deg_in_i  = deg_out_i + A;     // [A]  zeroed
  int*   cursor    = deg_in_i + A;      // [A]  written by scan3
  int*   offs      = cursor + A;        // [A]  (N+1 used, written by scan3)
  int*   bsum      = offs + A;          // [256]
  float* rs_out    = (float*)(bsum + 256);
  float* rs_in     = rs_out + A;
  int*   csr_src   = (int*)(rs_in + A); // [EA] (+slack: y follows, overreads safe)
  __half* y        = (__half*)(csr_src + EA); // [N*512] fp16, plain layout

  hipMemsetAsync(deg_out_i, 0, (size_t)(2 * A) * sizeof(int), stream);
  hipLaunchKernelGGL(k_deg, dim3((E + 255) / 256), dim3(256), 0, stream,
                     src, dst, deg_out_i, deg_in_i, E);
  hipLaunchKernelGGL(k_scan1, dim3(M), dim3(256), 0, stream,
                     deg_in_i, deg_out_i, bsum, rs_out, rs_in, N);
  hipLaunchKernelGGL(k_scan3, dim3(M), dim3(256), 0, stream,
                     deg_in_i, bsum, offs, cursor, M, N);
  hipLaunchKernelGGL(k_scatter, dim3((E + 255) / 256), dim3(256), 0, stream,
                     src, dst, cursor, csr_src, E);
  hipLaunchKernelGGL(k_transform, dim3(GX, 4), dim3(256), 0, stream,
                     in_feat, W, rs_out, y, N);
  hipLaunchKernelGGL(k_aggregate, dim3((N + 15) / 16), dim3(512), 0, stream,
                     y, offs, csr_src, rs_in, bvec, out, N);
}